// Round 1
// baseline (583.367 us; speedup 1.0000x reference)
//
#include <hip/hip_runtime.h>

// Unfold3d: x (4,32,16,48,48) fp32 -> out (4, 32*27, 16*48*48) fp32
// K=3, DIL=1, PAD=1, STR=1  => Do=16, Ho=48, Wo=48
//
// out flat index: (((bc*27 + p)*16 + do)*48 + ho)*48 + wo
//   bc = b*32 + c, p = kd*9 + kh*3 + kw
// value = x[bc][do+kd-1][ho+kh-1][wo+kw-1]  (0 if any index out of range)
//
// Memory-bound, write-dominated (510 MB out vs 38 MB in). One float4 store
// per work item; 4 bounds-checked scalar input reads (L2/L3-resident).

__global__ __launch_bounds__(256) void unfold3d_kernel(
    const float* __restrict__ x, float* __restrict__ out, int total4) {
  int idx = blockIdx.x * blockDim.x + threadIdx.x;
  const int stride = gridDim.x * blockDim.x;
  for (; idx < total4; idx += stride) {
    int t = idx;
    int wo4 = t % 12; t /= 12;          // float4 slot within the 48-wide row
    int ho  = t % 48; t /= 48;
    int dd  = t % 16; t /= 16;
    int p   = t % 27; int bc = t / 27;  // bc = b*32 + c

    int kd = p / 9;
    int r  = p - kd * 9;
    int kh = r / 3;
    int kw = r - kh * 3;

    int d = dd + kd - 1;
    int h = ho + kh - 1;
    int wbase = wo4 * 4 + kw - 1;

    float4 v = make_float4(0.f, 0.f, 0.f, 0.f);
    if ((unsigned)d < 16u && (unsigned)h < 48u) {
      const float* __restrict__ row = x + (((size_t)bc * 16 + d) * 48 + h) * 48;
      float vv[4];
#pragma unroll
      for (int j = 0; j < 4; ++j) {
        int w = wbase + j;
        vv[j] = ((unsigned)w < 48u) ? row[w] : 0.f;
      }
      v = make_float4(vv[0], vv[1], vv[2], vv[3]);
    }
    reinterpret_cast<float4*>(out)[idx] = v;
  }
}

extern "C" void kernel_launch(void* const* d_in, const int* in_sizes, int n_in,
                              void* d_out, int out_size, void* d_ws, size_t ws_size,
                              hipStream_t stream) {
  const float* x = (const float*)d_in[0];
  float* out = (float*)d_out;

  const int total4 = out_size / 4;  // 31,850,496 float4 items
  const int block = 256;
  int grid = (total4 + block - 1) / block;
  if (grid > 2048) grid = 2048;  // grid-stride the rest (G11)

  unfold3d_kernel<<<grid, block, 0, stream>>>(x, out, total4);
}